// Round 5
// baseline (299.977 us; speedup 1.0000x reference)
//
#include <hip/hip_runtime.h>
#include <math.h>

// Problem constants
constexpr int B = 8;
constexpr int D = 256;     // model dim
constexpr int C = 1024;    // expanded channels
constexpr int H = 32, W = 32;
constexpr int P = H * W;            // 1024 spatial positions
constexpr int M = B * P;            // 8192 rows
constexpr float EPS = 1e-5f;

typedef unsigned short u16;
typedef unsigned int u32;
typedef __attribute__((ext_vector_type(8))) short short8;
typedef __attribute__((ext_vector_type(4))) float floatx4;

// ---------------- workspace layout (in floats) ----------------
// zeroed accumulator region (atomics)
constexpr size_t WS_CHSUM1 = 0;                  // 1024
constexpr size_t WS_CHSQ1  = 1024;               // 1024
constexpr size_t WS_GAPSUM = 2048;               // 8192
constexpr size_t WS_CHSUM3 = 10240;              // 256
constexpr size_t WS_CHSQ3  = 10496;              // 256
constexpr size_t WS_ACC_COUNT = 10752;
// non-zeroed
constexpr size_t WS_SCALE1 = 11264;              // 1024
constexpr size_t WS_SHIFT1 = 12288;              // 1024
constexpr size_t WS_KW     = 21504;              // 256 (72 used)
constexpr size_t WS_SCALE2 = 21760;              // 1024
constexpr size_t WS_SHIFT2 = 22784;              // 1024
constexpr size_t WS_SATT   = 40192;              // 8192
constexpr size_t WS_AVGO   = 48384;              // 8192
constexpr size_t WS_MAXO   = 56576;              // 8192
constexpr size_t WS_SP     = 64768;              // 8192
constexpr size_t WS_PSUM2  = 73728;              // 262144  (partials [C][256], transposed)
constexpr size_t WS_PSQ2   = 335872;             // 262144
constexpr size_t WS_PMAX2  = 598016;             // 262144
constexpr size_t WS_PMIN2  = 860160;             // 262144
constexpr size_t WS_PRE    = 1122304;            // 2097152
constexpr size_t WS_T1B    = 3219456;            // bf16 t1: 8388608 u16 = 4194304 floats
constexpr size_t WS_T2B    = 7413760;            // bf16 t2: 4194304 floats
constexpr size_t WS_XB     = 11608064;           // bf16 x: 1048576 floats
constexpr size_t WS_W1B    = 12656640;           // 131072
constexpr size_t WS_PWB    = 12787712;           // 131072
constexpr size_t WS_YB     = 12918784;           // bf16 y: 4194304 floats
// total = 17113088 floats = 68.5 MB

__device__ __forceinline__ float gelu_exact(float v) {
    return 0.5f * v * (1.0f + erff(v * 0.70710678118654752440f));
}

__device__ __forceinline__ u16 f2bf(float f) {
    u32 u = __float_as_uint(f);
    u += 0x7fff + ((u >> 16) & 1);   // round-to-nearest-even
    return (u16)(u >> 16);
}

__device__ __forceinline__ float bf2f(u16 v) {
    return __uint_as_float(((u32)v) << 16);
}

// ---------------- K0: fused cast fp32 -> bf16 for x, w1, pw ----------------
// float4-unit counts: x 524288, w1 65536, pw 65536  (total 655360)
__global__ __launch_bounds__(256) void cvt_all_kernel(const float* __restrict__ x,
                                                      const float* __restrict__ w1,
                                                      const float* __restrict__ pw,
                                                      u16* __restrict__ xb,
                                                      u16* __restrict__ w1b,
                                                      u16* __restrict__ pwb) {
    const int i = blockIdx.x * 256 + threadIdx.x;
    const float* src;
    u16* dst;
    int off;
    if (i < 524288)      { src = x;  dst = xb;  off = i; }
    else if (i < 589824) { src = w1; dst = w1b; off = i - 524288; }
    else                 { src = pw; dst = pwb; off = i - 589824; }
    const float4 v = *(const float4*)(src + (size_t)off * 4);
    uint2 o;
    o.x = ((u32)f2bf(v.x)) | ((u32)f2bf(v.y) << 16);
    o.y = ((u32)f2bf(v.z)) | ((u32)f2bf(v.w) << 16);
    *(uint2*)(dst + (size_t)off * 4) = o;
}

// ---------------- MFMA bf16 GEMM + fused epilogue + fused column stats ----------------
// 128xNB tile, BK=32, global_load_lds width=16, 4 waves of 64x(NB/2).
// EPI 0 (gemm1): t = gelu(acc + bias[col]); store bf16; stats -> sum/sq/gsum[b*NS+col]
// EPI 1 (gemm2): t = rowscale[row]*acc + bias[col]; store fp32; stats -> sum/sq
template<int KD, int EPI, int NS, int NB>
__global__ __launch_bounds__(256) void mfma_gemm_kernel(
    const u16* __restrict__ A,
    const u16* __restrict__ Bw,
    const float* __restrict__ bias,
    const float* __restrict__ rowscale,
    void* __restrict__ outv,
    float* __restrict__ csum,
    float* __restrict__ csq,
    float* __restrict__ gsum)
{
    constexpr int NJ = NB / 32;               // accum col-blocks per wave
    __shared__ u16 As[128 * 32];
    __shared__ u16 Bs[NB * 32];
    const int t = threadIdx.x;
    const int lane = t & 63;
    const int row0 = blockIdx.y * 128;
    const int col0 = blockIdx.x * NB;
    const int wv = t >> 6;
    const int wrow = (wv >> 1) * 64;
    const int wcol = (wv & 1) * (NB / 2);
    const int lm = lane & 15;
    const int lk8 = (lane >> 4) * 8;

    const int srow = t >> 2;
    const int scol = (t & 3) * 8;

    const u16* gA0 = A + (size_t)(row0 + srow) * KD + scol;
    const u16* gA1 = A + (size_t)(row0 + 64 + srow) * KD + scol;
    const u16* gB0 = Bw + (size_t)(col0 + srow) * KD + scol;
    const u16* gB1 = Bw + (size_t)(col0 + ((NB == 128) ? 64 : 0) + srow) * KD + scol;

    const floatx4 zero = {0.f, 0.f, 0.f, 0.f};
    floatx4 acc[4][NJ];
#pragma unroll
    for (int i = 0; i < 4; ++i)
#pragma unroll
        for (int j = 0; j < NJ; ++j) acc[i][j] = zero;

    for (int k0 = 0; k0 < KD; k0 += 32) {
        __builtin_amdgcn_global_load_lds(
            (const __attribute__((address_space(1))) void*)(gA0 + k0),
            (__attribute__((address_space(3))) void*)(As + t * 8), 16, 0, 0);
        __builtin_amdgcn_global_load_lds(
            (const __attribute__((address_space(1))) void*)(gA1 + k0),
            (__attribute__((address_space(3))) void*)(As + 2048 + t * 8), 16, 0, 0);
        __builtin_amdgcn_global_load_lds(
            (const __attribute__((address_space(1))) void*)(gB0 + k0),
            (__attribute__((address_space(3))) void*)(Bs + t * 8), 16, 0, 0);
        if (NB == 128)
            __builtin_amdgcn_global_load_lds(
                (const __attribute__((address_space(1))) void*)(gB1 + k0),
                (__attribute__((address_space(3))) void*)(Bs + 2048 + t * 8), 16, 0, 0);
        __syncthreads();
        short8 af[4], bf[NJ];
#pragma unroll
        for (int i = 0; i < 4; ++i)
            af[i] = *(const short8*)(As + (wrow + i * 16 + lm) * 32 + lk8);
#pragma unroll
        for (int j = 0; j < NJ; ++j)
            bf[j] = *(const short8*)(Bs + (wcol + j * 16 + lm) * 32 + lk8);
#pragma unroll
        for (int i = 0; i < 4; ++i)
#pragma unroll
            for (int j = 0; j < NJ; ++j)
                acc[i][j] = __builtin_amdgcn_mfma_f32_16x16x32_bf16(af[i], bf[j], acc[i][j], 0, 0, 0);
        __syncthreads();
    }

    // C/D layout: col = lane&15, row = (lane>>4)*4 + reg
    float colsum[NJ], colsq[NJ];
#pragma unroll
    for (int j = 0; j < NJ; ++j) { colsum[j] = 0.f; colsq[j] = 0.f; }
#pragma unroll
    for (int i = 0; i < 4; ++i) {
#pragma unroll
        for (int r = 0; r < 4; ++r) {
            const int grow = row0 + wrow + i * 16 + (lane >> 4) * 4 + r;
            float rs = 0.f;
            if (EPI == 1) rs = rowscale[grow];
#pragma unroll
            for (int j = 0; j < NJ; ++j) {
                const int gcol = col0 + wcol + j * 16 + lm;
                const float v = acc[i][j][r];
                float tv;
                if (EPI == 0) {
                    tv = gelu_exact(v + bias[gcol]);
                    ((u16*)outv)[(size_t)grow * NS + gcol] = f2bf(tv);
                } else {
                    tv = rs * v + bias[gcol];
                    ((float*)outv)[(size_t)grow * NS + gcol] = tv;
                }
                colsum[j] += tv;
                colsq[j] = fmaf(tv, tv, colsq[j]);
            }
        }
    }
    const int bb = blockIdx.y >> 3;   // batch index (128 rows/block, 8 blocks/batch)
#pragma unroll
    for (int j = 0; j < NJ; ++j) {
        float s = colsum[j];
        float q = colsq[j];
        s += __shfl_xor(s, 16); s += __shfl_xor(s, 32);
        q += __shfl_xor(q, 16); q += __shfl_xor(q, 32);
        if (lane < 16) {
            const int c = col0 + wcol + j * 16 + lm;
            atomicAdd(&csum[c], s);
            atomicAdd(&csq[c], q);
            if (EPI == 0) atomicAdd(&gsum[bb * NS + c], s);
        }
    }
}

// ---------------- K4: dynamic kernel MLP + fused BN1 stats ----------------
__global__ __launch_bounds__(1024) void dynmlp_kernel(const float* __restrict__ chsum1,
                                                      const float* __restrict__ chsq1,
                                                      const float* __restrict__ gapsum,
                                                      const float* __restrict__ g1,
                                                      const float* __restrict__ be1,
                                                      const float* __restrict__ aw1,
                                                      const float* __restrict__ ab1,
                                                      const float* __restrict__ aw2,
                                                      const float* __restrict__ ab2,
                                                      float* __restrict__ scale1,
                                                      float* __restrict__ shift1,
                                                      float* __restrict__ kw) {
    const int b = blockIdx.x;
    const int t = threadIdx.x;
    const int wave = t >> 6, lane = t & 63;
    __shared__ float g[1024];
    __shared__ float h1[128];
    __shared__ float logits[12];
    {
        const float m = chsum1[t] * (1.0f / (float)M);
        const float var = chsq1[t] * (1.0f / (float)M) - m * m;
        const float rstd = rsqrtf(var + EPS);
        const float sc = rstd * g1[t];
        const float sh = be1[t] - m * sc;
        if (b == 0) { scale1[t] = sc; shift1[t] = sh; }
        g[t] = gapsum[b * C + t] * (1.0f / (float)P) * sc + sh;
    }
    __syncthreads();
    // layer1: 128 units, one per (wave, k)
#pragma unroll
    for (int k = 0; k < 8; ++k) {
        const int u = wave * 8 + k;
        const float4* wr = (const float4*)(aw1 + (size_t)u * C);
        float s = 0.f;
#pragma unroll
        for (int ch = 0; ch < 4; ++ch) {
            const float4 wv = wr[lane + 64 * ch];
            const float4 sv = *(const float4*)(g + 4 * lane + 256 * ch);
            s += wv.x * sv.x + wv.y * sv.y + wv.z * sv.z + wv.w * sv.w;
        }
#pragma unroll
        for (int off = 1; off < 64; off <<= 1) s += __shfl_xor(s, off);
        if (lane == 0) h1[u] = fmaxf(s + ab1[u], 0.f);
    }
    __syncthreads();
    // layer2: 9 logits, one wave each
    if (wave < 9) {
        float s = aw2[wave * 128 + lane] * h1[lane]
                + aw2[wave * 128 + 64 + lane] * h1[64 + lane];
#pragma unroll
        for (int off = 1; off < 64; off <<= 1) s += __shfl_xor(s, off);
        if (lane == 0) logits[wave] = s + ab2[wave];
    }
    __syncthreads();
    if (t == 0) {
        float mx = logits[0];
        for (int i = 1; i < 9; ++i) mx = fmaxf(mx, logits[i]);
        float e[9], den = 0.f;
        for (int i = 0; i < 9; ++i) { e[i] = expf(logits[i] - mx); den += e[i]; }
        const float inv = 1.0f / den;
        for (int i = 0; i < 9; ++i) kw[b * 9 + i] = e[i] * inv;
    }
}

// ---------------- K5: dyn depthwise conv, sliding window, 2 channels/thread ----------------
// partials stored transposed: p*[c*256 + b*32 + h]
__global__ __launch_bounds__(256) void dwconv_kernel(const u16* __restrict__ t1b,
                                                     const float* __restrict__ scale1,
                                                     const float* __restrict__ shift1,
                                                     const float* __restrict__ kw,
                                                     u16* __restrict__ t2b,
                                                     float* __restrict__ psum,
                                                     float* __restrict__ psq,
                                                     float* __restrict__ pmax,
                                                     float* __restrict__ pmin) {
    const int b = blockIdx.y >> 5;
    const int h = blockIdx.y & 31;
    const int c0 = (blockIdx.x * 256 + threadIdx.x) * 2;
    float k[9];
#pragma unroll
    for (int i = 0; i < 9; ++i) k[i] = kw[b * 9 + i];
    const float sc0 = scale1[c0],     sh0 = shift1[c0];
    const float sc1 = scale1[c0 + 1], sh1 = shift1[c0 + 1];
    const u16* base = t1b + (size_t)b * P * C + c0;
    const bool rok[3] = { h > 0, true, h < H - 1 };

    float2 win[3][3];
    const float2 z = {0.f, 0.f};
#pragma unroll
    for (int ri = 0; ri < 3; ++ri) {
        win[ri][0] = z;
#pragma unroll
        for (int ci = 1; ci < 3; ++ci) {
            if (rok[ri]) {
                const u32 v = *(const u32*)(base + ((size_t)((h + ri - 1) * W + (ci - 1))) * C);
                float2 r;
                r.x = fmaf(bf2f((u16)(v & 0xffff)), sc0, sh0);
                r.y = fmaf(bf2f((u16)(v >> 16)),    sc1, sh1);
                win[ri][ci] = r;
            } else win[ri][ci] = z;
        }
    }

    float s0 = 0.f, q0 = 0.f, mx0 = -INFINITY, mn0 = INFINITY;
    float s1 = 0.f, q1 = 0.f, mx1 = -INFINITY, mn1 = INFINITY;
    for (int w = 0; w < W; ++w) {
        float a0 = 0.f, a1 = 0.f;
#pragma unroll
        for (int ri = 0; ri < 3; ++ri)
#pragma unroll
            for (int ci = 0; ci < 3; ++ci) {
                a0 = fmaf(k[ri * 3 + ci], win[ri][ci].x, a0);
                a1 = fmaf(k[ri * 3 + ci], win[ri][ci].y, a1);
            }
        const float y0 = gelu_exact(a0);
        const float y1 = gelu_exact(a1);
        *(u32*)(t2b + ((size_t)b * P + h * W + w) * C + c0) =
            ((u32)f2bf(y0)) | ((u32)f2bf(y1) << 16);
        s0 += y0; q0 = fmaf(y0, y0, q0); mx0 = fmaxf(mx0, y0); mn0 = fminf(mn0, y0);
        s1 += y1; q1 = fmaf(y1, y1, q1); mx1 = fmaxf(mx1, y1); mn1 = fminf(mn1, y1);
        // slide window
        if (w < W - 1) {
#pragma unroll
            for (int ri = 0; ri < 3; ++ri) {
                win[ri][0] = win[ri][1];
                win[ri][1] = win[ri][2];
                if (rok[ri] && (w + 2 < W)) {
                    const u32 v = *(const u32*)(base + ((size_t)((h + ri - 1) * W + (w + 2))) * C);
                    float2 r;
                    r.x = fmaf(bf2f((u16)(v & 0xffff)), sc0, sh0);
                    r.y = fmaf(bf2f((u16)(v >> 16)),    sc1, sh1);
                    win[ri][2] = r;
                } else win[ri][2] = z;
            }
        }
    }
    const int idx = b * 32 + h;
    psum[c0 * 256 + idx] = s0;  psum[(c0 + 1) * 256 + idx] = s1;
    psq [c0 * 256 + idx] = q0;  psq [(c0 + 1) * 256 + idx] = q1;
    pmax[c0 * 256 + idx] = mx0; pmax[(c0 + 1) * 256 + idx] = mx1;
    pmin[c0 * 256 + idx] = mn0; pmin[(c0 + 1) * 256 + idx] = mn1;
}

// ---------------- K8: channel attention + fused BN2 stats ----------------
__global__ __launch_bounds__(1024) void chatt_kernel(const float* __restrict__ psum,
                                                     const float* __restrict__ psq,
                                                     const float* __restrict__ pmax,
                                                     const float* __restrict__ pmin,
                                                     const float* __restrict__ g2,
                                                     const float* __restrict__ be2,
                                                     const float* __restrict__ caw1,
                                                     const float* __restrict__ caw2,
                                                     float* __restrict__ scale2,
                                                     float* __restrict__ shift2,
                                                     float* __restrict__ s_att) {
    const int b = blockIdx.x;
    const int t = threadIdx.x;          // t = channel
    const int wave = t >> 6, lane = t & 63;
    __shared__ float la[1024], lx[1024], ha[64], hm[64];
    {
        // global sum/sq over all 256 partials of channel t
        const float4* ps4 = (const float4*)(psum + (size_t)t * 256);
        const float4* pq4 = (const float4*)(psq + (size_t)t * 256);
        float S = 0.f, Q = 0.f;
#pragma unroll 8
        for (int i = 0; i < 64; ++i) {
            const float4 a = ps4[i];
            S += (a.x + a.y) + (a.z + a.w);
            const float4 qv = pq4[i];
            Q += (qv.x + qv.y) + (qv.z + qv.w);
        }
        // own batch's 32 partials: sum + max/min
        float bs = 0.f, bmx = -INFINITY, bmn = INFINITY;
        const float4* bps = (const float4*)(psum + (size_t)t * 256 + b * 32);
        const float4* bmx4 = (const float4*)(pmax + (size_t)t * 256 + b * 32);
        const float4* bmn4 = (const float4*)(pmin + (size_t)t * 256 + b * 32);
#pragma unroll
        for (int i = 0; i < 8; ++i) {
            const float4 a = bps[i];
            bs += (a.x + a.y) + (a.z + a.w);
            const float4 xv = bmx4[i];
            bmx = fmaxf(bmx, fmaxf(fmaxf(xv.x, xv.y), fmaxf(xv.z, xv.w)));
            const float4 nv = bmn4[i];
            bmn = fminf(bmn, fminf(fminf(nv.x, nv.y), fminf(nv.z, nv.w)));
        }
        const float m = S * (1.0f / (float)M);
        const float var = Q * (1.0f / (float)M) - m * m;
        const float rstd = rsqrtf(var + EPS);
        const float sc = rstd * g2[t];
        const float sh = be2[t] - m * sc;
        if (b == 0) { scale2[t] = sc; shift2[t] = sh; }
        la[t] = bs * (1.0f / (float)P) * sc + sh;
        lx[t] = (sc >= 0.f ? bmx : bmn) * sc + sh;
    }
    __syncthreads();
    // layer1: 128 units (64 avg + 64 max), one per (wave, k)
#pragma unroll
    for (int k = 0; k < 8; ++k) {
        const int u = wave * 8 + k;
        const int row = u & 63;
        const float* src = (u < 64) ? la : lx;
        const float4* wr = (const float4*)(caw1 + (size_t)row * C);
        float s = 0.f;
#pragma unroll
        for (int ch = 0; ch < 4; ++ch) {
            const float4 wv = wr[lane + 64 * ch];
            const float4 sv = *(const float4*)(src + 4 * lane + 256 * ch);
            s += wv.x * sv.x + wv.y * sv.y + wv.z * sv.z + wv.w * sv.w;
        }
#pragma unroll
        for (int off = 1; off < 64; off <<= 1) s += __shfl_xor(s, off);
        if (lane == 0) {
            s = fmaxf(s, 0.f);
            if (u < 64) ha[row] = s; else hm[row] = s;
        }
    }
    __syncthreads();
    // layer2: 1024 outputs, one per thread (64-length dot from LDS)
    {
        const float4* w2 = (const float4*)(caw2 + (size_t)t * 64);
        float s = 0.f;
#pragma unroll
        for (int j = 0; j < 16; ++j) {
            const float4 wv = w2[j];
            s += wv.x * (ha[j * 4 + 0] + hm[j * 4 + 0]);
            s += wv.y * (ha[j * 4 + 1] + hm[j * 4 + 1]);
            s += wv.z * (ha[j * 4 + 2] + hm[j * 4 + 2]);
            s += wv.w * (ha[j * 4 + 3] + hm[j * 4 + 3]);
        }
        s_att[b * C + t] = 1.0f / (1.0f + expf(-s));
    }
}

// ---------------- K9: y = s_att*bn2(t2) -> bf16 yb + per-row avg/max ----------------
__global__ __launch_bounds__(256) void yq_kernel(const u16* __restrict__ t2b,
                                                 const float* __restrict__ scale2,
                                                 const float* __restrict__ shift2,
                                                 const float* __restrict__ s_att,
                                                 u16* __restrict__ yb,
                                                 float* __restrict__ avg_o,
                                                 float* __restrict__ max_o) {
    const int row = blockIdx.x;       // b*P + p
    const int b = row >> 10;
    const int t = threadIdx.x;
    const int c0 = t * 4;
    const uint2 vv = *(const uint2*)(t2b + (size_t)row * C + c0);
    const float v0 = bf2f((u16)(vv.x & 0xffff));
    const float v1 = bf2f((u16)(vv.x >> 16));
    const float v2 = bf2f((u16)(vv.y & 0xffff));
    const float v3 = bf2f((u16)(vv.y >> 16));
    const float4 sc = *(const float4*)(scale2 + c0);
    const float4 sh = *(const float4*)(shift2 + c0);
    const float4 sa = *(const float4*)(s_att + (size_t)b * C + c0);
    const float y0 = fmaf(v0, sc.x, sh.x) * sa.x;
    const float y1 = fmaf(v1, sc.y, sh.y) * sa.y;
    const float y2 = fmaf(v2, sc.z, sh.z) * sa.z;
    const float y3 = fmaf(v3, sc.w, sh.w) * sa.w;
    uint2 o;
    o.x = ((u32)f2bf(y0)) | ((u32)f2bf(y1) << 16);
    o.y = ((u32)f2bf(y2)) | ((u32)f2bf(y3) << 16);
    *(uint2*)(yb + (size_t)row * C + c0) = o;
    float s = (y0 + y1) + (y2 + y3);
    float mx = fmaxf(fmaxf(y0, y1), fmaxf(y2, y3));
#pragma unroll
    for (int off = 32; off > 0; off >>= 1) {
        s += __shfl_down(s, off);
        mx = fmaxf(mx, __shfl_down(mx, off));
    }
    __shared__ float ss[4], sm[4];
    const int wave = t >> 6, lane = t & 63;
    if (lane == 0) { ss[wave] = s; sm[wave] = mx; }
    __syncthreads();
    if (t == 0) {
        const float S = ss[0] + ss[1] + ss[2] + ss[3];
        const float Mx = fmaxf(fmaxf(sm[0], sm[1]), fmaxf(sm[2], sm[3]));
        avg_o[row] = S * (1.0f / (float)C);
        max_o[row] = Mx;
    }
}

// ---------------- K10: 7x7 spatial conv + sigmoid (1 pixel/thread) ----------------
__global__ __launch_bounds__(1024) void spconv_kernel(const float* __restrict__ avg_o,
                                                      const float* __restrict__ max_o,
                                                      const float* __restrict__ sw,
                                                      const float* __restrict__ sb,
                                                      float* __restrict__ sp) {
    const int b = blockIdx.x;
    const int t = threadIdx.x;
    __shared__ float pa[P], pm[P], wsh[98];
    pa[t] = avg_o[b * P + t];
    pm[t] = max_o[b * P + t];
    if (t < 98) wsh[t] = sw[t];
    const float sbv = sb[0];
    __syncthreads();
    const int h = t >> 5, w = t & 31;
    float acc = sbv;
#pragma unroll
    for (int i = 0; i < 7; ++i) {
        const int hh = h + i - 3;
        if (hh < 0 || hh >= H) continue;
#pragma unroll
        for (int j = 0; j < 7; ++j) {
            const int ww = w + j - 3;
            if (ww < 0 || ww >= W) continue;
            const int pidx = hh * W + ww;
            acc = fmaf(wsh[i * 7 + j], pa[pidx], acc);
            acc = fmaf(wsh[49 + i * 7 + j], pm[pidx], acc);
        }
    }
    sp[b * P + t] = 1.0f / (1.0f + expf(-acc));
}

// ---------------- K15: final residual add + fused BN3 stats ----------------
__global__ __launch_bounds__(256) void final_kernel(const float* __restrict__ x,
                                                    const float* __restrict__ pre,
                                                    const float* __restrict__ chsum3,
                                                    const float* __restrict__ chsq3,
                                                    const float* __restrict__ g3,
                                                    const float* __restrict__ be3,
                                                    float* __restrict__ out) {
    __shared__ float lsc[256], lsh[256];
    const int t = threadIdx.x;
    {
        const float m = chsum3[t] * (1.0f / (float)M);
        const float var = chsq3[t] * (1.0f / (float)M) - m * m;
        const float rstd = rsqrtf(var + EPS);
        const float sc = rstd * g3[t];
        lsc[t] = sc;
        lsh[t] = be3[t] - m * sc;
    }
    __syncthreads();
    const int i = blockIdx.x * 256 + t;   // float4 index
    const int e = i * 4;
    const int d = e & 255;
    const float4 xv = *(const float4*)(x + e);
    const float4 pv = *(const float4*)(pre + e);
    const float4 sc = *(const float4*)(lsc + d);
    const float4 sh = *(const float4*)(lsh + d);
    float4 o;
    o.x = xv.x + fmaf(pv.x, sc.x, sh.x);
    o.y = xv.y + fmaf(pv.y, sc.y, sh.y);
    o.z = xv.z + fmaf(pv.z, sc.z, sh.z);
    o.w = xv.w + fmaf(pv.w, sc.w, sh.w);
    *(float4*)(out + e) = o;
}

extern "C" void kernel_launch(void* const* d_in, const int* in_sizes, int n_in,
                              void* d_out, int out_size, void* d_ws, size_t ws_size,
                              hipStream_t stream) {
    const float* x    = (const float*)d_in[0];
    const float* w1   = (const float*)d_in[1];
    const float* b1   = (const float*)d_in[2];
    const float* g1   = (const float*)d_in[3];
    const float* be1  = (const float*)d_in[4];
    const float* aw1  = (const float*)d_in[5];
    const float* ab1  = (const float*)d_in[6];
    const float* aw2  = (const float*)d_in[7];
    const float* ab2  = (const float*)d_in[8];
    const float* g2   = (const float*)d_in[9];
    const float* be2  = (const float*)d_in[10];
    const float* caw1 = (const float*)d_in[11];
    const float* caw2 = (const float*)d_in[12];
    const float* pw   = (const float*)d_in[13];
    const float* pb   = (const float*)d_in[14];
    const float* g3   = (const float*)d_in[15];
    const float* be3  = (const float*)d_in[16];
    const float* sw   = (const float*)d_in[17];
    const float* sb   = (const float*)d_in[18];
    float* out = (float*)d_out;
    float* ws = (float*)d_ws;

    // zero atomic accumulators
    hipMemsetAsync(ws, 0, WS_ACC_COUNT * sizeof(float), stream);

    float* chsum1  = ws + WS_CHSUM1;
    float* chsq1   = ws + WS_CHSQ1;
    float* gapsum  = ws + WS_GAPSUM;
    float* chsum3  = ws + WS_CHSUM3;
    float* chsq3   = ws + WS_CHSQ3;
    float* scale1  = ws + WS_SCALE1;
    float* shift1  = ws + WS_SHIFT1;
    float* kw      = ws + WS_KW;
    float* scale2  = ws + WS_SCALE2;
    float* shift2  = ws + WS_SHIFT2;
    float* s_att   = ws + WS_SATT;
    float* avg_o   = ws + WS_AVGO;
    float* max_o   = ws + WS_MAXO;
    float* sp      = ws + WS_SP;
    float* psum2   = ws + WS_PSUM2;
    float* psq2    = ws + WS_PSQ2;
    float* pmax2   = ws + WS_PMAX2;
    float* pmin2   = ws + WS_PMIN2;
    float* pre     = ws + WS_PRE;
    u16* t1b = (u16*)(ws + WS_T1B);
    u16* t2b = (u16*)(ws + WS_T2B);
    u16* xb  = (u16*)(ws + WS_XB);
    u16* w1b = (u16*)(ws + WS_W1B);
    u16* pwb = (u16*)(ws + WS_PWB);
    u16* yb  = (u16*)(ws + WS_YB);

    // K0: all casts in one launch (655360 float4 units)
    cvt_all_kernel<<<dim3(2560), 256, 0, stream>>>(x, w1, pw, xb, w1b, pwb);
    // K1: expand GEMM (bf16 MFMA) + bias + GELU -> bf16 t1, fused BN1 partial stats
    mfma_gemm_kernel<256, 0, C, 128><<<dim3(C / 128, M / 128), 256, 0, stream>>>(
        xb, w1b, b1, nullptr, t1b, chsum1, chsq1, gapsum);
    // K4: BN1 stats + gap + dynamic kernel weights (fused)
    dynmlp_kernel<<<dim3(B), 1024, 0, stream>>>(chsum1, chsq1, gapsum, g1, be1,
                                                aw1, ab1, aw2, ab2, scale1, shift1, kw);
    // K5: depthwise conv + GELU -> bf16 t2, fused BN2 partials (transposed layout)
    dwconv_kernel<<<dim3(C / 512, B * H), 256, 0, stream>>>(t1b, scale1, shift1, kw, t2b,
                                                            psum2, psq2, pmax2, pmin2);
    // K8: BN2 stats + channel attention (fused)
    chatt_kernel<<<dim3(B), 1024, 0, stream>>>(psum2, psq2, pmax2, pmin2, g2, be2,
                                               caw1, caw2, scale2, shift2, s_att);
    // K9: y quantize + spatial stats
    yq_kernel<<<dim3(M), 256, 0, stream>>>(t2b, scale2, shift2, s_att, yb, avg_o, max_o);
    // K10: 7x7 conv + sigmoid
    spconv_kernel<<<dim3(B), 1024, 0, stream>>>(avg_o, max_o, sw, sb, sp);
    // K12: project GEMM (bf16 MFMA, 128x64 tile) + sp/bias epilogue -> fp32 pre, fused BN3 stats
    mfma_gemm_kernel<1024, 1, D, 64><<<dim3(D / 64, M / 128), 256, 0, stream>>>(
        yb, pwb, pb, sp, pre, chsum3, chsq3, nullptr);
    // K15: BN3 stats + final residual add (fused)
    final_kernel<<<dim3((M * D / 4) / 256), 256, 0, stream>>>(x, pre, chsum3, chsq3, g3, be3, out);
}

// Round 6
// 223.615 us; speedup vs baseline: 1.3415x; 1.3415x over previous
//
#include <hip/hip_runtime.h>
#include <math.h>

// Problem constants
constexpr int B = 8;
constexpr int D = 256;     // model dim
constexpr int C = 1024;    // expanded channels
constexpr int H = 32, W = 32;
constexpr int P = H * W;            // 1024 spatial positions
constexpr int M = B * P;            // 8192 rows
constexpr float EPS = 1e-5f;

typedef unsigned short u16;
typedef unsigned int u32;
typedef __attribute__((ext_vector_type(8))) short short8;
typedef __attribute__((ext_vector_type(4))) float floatx4;

// ---------------- workspace layout (in floats) ----------------
// zeroed accumulator region (atomics)
constexpr size_t WS_CHSUM1 = 0;                  // 1024
constexpr size_t WS_CHSQ1  = 1024;               // 1024
constexpr size_t WS_GAPSUM = 2048;               // 8192
constexpr size_t WS_CHSUM3 = 10240;              // 256
constexpr size_t WS_CHSQ3  = 10496;              // 256
constexpr size_t WS_ACC_COUNT = 10752;
// non-zeroed
constexpr size_t WS_SCALE1 = 11264;              // 1024
constexpr size_t WS_SHIFT1 = 12288;              // 1024
constexpr size_t WS_KW     = 21504;              // 256 (72 used)
constexpr size_t WS_SCALE2 = 21760;              // 1024
constexpr size_t WS_SHIFT2 = 22784;              // 1024
constexpr size_t WS_AVGBN  = 23808;              // 8192
constexpr size_t WS_MXBN   = 32000;              // 8192
constexpr size_t WS_SATT   = 40192;              // 8192
constexpr size_t WS_AVGO   = 48384;              // 8192
constexpr size_t WS_MAXO   = 56576;              // 8192
constexpr size_t WS_SP     = 64768;              // 8192
constexpr size_t WS_PSUM2  = 73728;              // 262144  (partials [C][256], transposed)
constexpr size_t WS_PSQ2   = 335872;             // 262144
constexpr size_t WS_PMAX2  = 598016;             // 262144
constexpr size_t WS_PMIN2  = 860160;             // 262144
constexpr size_t WS_PRE    = 1122304;            // 2097152
constexpr size_t WS_T1B    = 3219456;            // bf16 t1: 8388608 u16 = 4194304 floats
constexpr size_t WS_T2B    = 7413760;            // bf16 t2: 4194304 floats
constexpr size_t WS_XB     = 11608064;           // bf16 x: 1048576 floats
constexpr size_t WS_W1B    = 12656640;           // 131072
constexpr size_t WS_PWB    = 12787712;           // 131072
constexpr size_t WS_YB     = 12918784;           // bf16 y: 4194304 floats
// total = 17113088 floats = 68.5 MB

__device__ __forceinline__ float gelu_exact(float v) {
    return 0.5f * v * (1.0f + erff(v * 0.70710678118654752440f));
}

__device__ __forceinline__ u16 f2bf(float f) {
    u32 u = __float_as_uint(f);
    u += 0x7fff + ((u >> 16) & 1);   // round-to-nearest-even
    return (u16)(u >> 16);
}

__device__ __forceinline__ float bf2f(u16 v) {
    return __uint_as_float(((u32)v) << 16);
}

// ---------------- K0: fused cast fp32 -> bf16 for x, w1, pw ----------------
// float4-unit counts: x 524288, w1 65536, pw 65536  (total 655360)
__global__ __launch_bounds__(256) void cvt_all_kernel(const float* __restrict__ x,
                                                      const float* __restrict__ w1,
                                                      const float* __restrict__ pw,
                                                      u16* __restrict__ xb,
                                                      u16* __restrict__ w1b,
                                                      u16* __restrict__ pwb) {
    const int i = blockIdx.x * 256 + threadIdx.x;
    const float* src;
    u16* dst;
    int off;
    if (i < 524288)      { src = x;  dst = xb;  off = i; }
    else if (i < 589824) { src = w1; dst = w1b; off = i - 524288; }
    else                 { src = pw; dst = pwb; off = i - 589824; }
    const float4 v = *(const float4*)(src + (size_t)off * 4);
    uint2 o;
    o.x = ((u32)f2bf(v.x)) | ((u32)f2bf(v.y) << 16);
    o.y = ((u32)f2bf(v.z)) | ((u32)f2bf(v.w) << 16);
    *(uint2*)(dst + (size_t)off * 4) = o;
}

// ---------------- MFMA bf16 GEMM + fused epilogue + fused column stats ----------------
// 128xNB tile, BK=32, global_load_lds width=16, 4 waves of 64x(NB/2).
// EPI 0 (gemm1): t = gelu(acc + bias[col]); store bf16; stats -> sum/sq/gsum[b*NS+col]
// EPI 1 (gemm2): t = rowscale[row]*acc + bias[col]; store fp32; stats -> sum/sq
template<int KD, int EPI, int NS, int NB>
__global__ __launch_bounds__(256) void mfma_gemm_kernel(
    const u16* __restrict__ A,
    const u16* __restrict__ Bw,
    const float* __restrict__ bias,
    const float* __restrict__ rowscale,
    void* __restrict__ outv,
    float* __restrict__ csum,
    float* __restrict__ csq,
    float* __restrict__ gsum)
{
    constexpr int NJ = NB / 32;               // accum col-blocks per wave
    __shared__ u16 As[128 * 32];
    __shared__ u16 Bs[NB * 32];
    const int t = threadIdx.x;
    const int lane = t & 63;
    const int row0 = blockIdx.y * 128;
    const int col0 = blockIdx.x * NB;
    const int wv = t >> 6;
    const int wrow = (wv >> 1) * 64;
    const int wcol = (wv & 1) * (NB / 2);
    const int lm = lane & 15;
    const int lk8 = (lane >> 4) * 8;

    const int srow = t >> 2;
    const int scol = (t & 3) * 8;

    const u16* gA0 = A + (size_t)(row0 + srow) * KD + scol;
    const u16* gA1 = A + (size_t)(row0 + 64 + srow) * KD + scol;
    const u16* gB0 = Bw + (size_t)(col0 + srow) * KD + scol;
    const u16* gB1 = Bw + (size_t)(col0 + ((NB == 128) ? 64 : 0) + srow) * KD + scol;

    const floatx4 zero = {0.f, 0.f, 0.f, 0.f};
    floatx4 acc[4][NJ];
#pragma unroll
    for (int i = 0; i < 4; ++i)
#pragma unroll
        for (int j = 0; j < NJ; ++j) acc[i][j] = zero;

    for (int k0 = 0; k0 < KD; k0 += 32) {
        __builtin_amdgcn_global_load_lds(
            (const __attribute__((address_space(1))) void*)(gA0 + k0),
            (__attribute__((address_space(3))) void*)(As + t * 8), 16, 0, 0);
        __builtin_amdgcn_global_load_lds(
            (const __attribute__((address_space(1))) void*)(gA1 + k0),
            (__attribute__((address_space(3))) void*)(As + 2048 + t * 8), 16, 0, 0);
        __builtin_amdgcn_global_load_lds(
            (const __attribute__((address_space(1))) void*)(gB0 + k0),
            (__attribute__((address_space(3))) void*)(Bs + t * 8), 16, 0, 0);
        if (NB == 128)
            __builtin_amdgcn_global_load_lds(
                (const __attribute__((address_space(1))) void*)(gB1 + k0),
                (__attribute__((address_space(3))) void*)(Bs + 2048 + t * 8), 16, 0, 0);
        __syncthreads();
        short8 af[4], bf[NJ];
#pragma unroll
        for (int i = 0; i < 4; ++i)
            af[i] = *(const short8*)(As + (wrow + i * 16 + lm) * 32 + lk8);
#pragma unroll
        for (int j = 0; j < NJ; ++j)
            bf[j] = *(const short8*)(Bs + (wcol + j * 16 + lm) * 32 + lk8);
#pragma unroll
        for (int i = 0; i < 4; ++i)
#pragma unroll
            for (int j = 0; j < NJ; ++j)
                acc[i][j] = __builtin_amdgcn_mfma_f32_16x16x32_bf16(af[i], bf[j], acc[i][j], 0, 0, 0);
        __syncthreads();
    }

    // C/D layout: col = lane&15, row = (lane>>4)*4 + reg
    float colsum[NJ], colsq[NJ];
#pragma unroll
    for (int j = 0; j < NJ; ++j) { colsum[j] = 0.f; colsq[j] = 0.f; }
#pragma unroll
    for (int i = 0; i < 4; ++i) {
#pragma unroll
        for (int r = 0; r < 4; ++r) {
            const int grow = row0 + wrow + i * 16 + (lane >> 4) * 4 + r;
            float rs = 0.f;
            if (EPI == 1) rs = rowscale[grow];
#pragma unroll
            for (int j = 0; j < NJ; ++j) {
                const int gcol = col0 + wcol + j * 16 + lm;
                const float v = acc[i][j][r];
                float tv;
                if (EPI == 0) {
                    tv = gelu_exact(v + bias[gcol]);
                    ((u16*)outv)[(size_t)grow * NS + gcol] = f2bf(tv);
                } else {
                    tv = rs * v + bias[gcol];
                    ((float*)outv)[(size_t)grow * NS + gcol] = tv;
                }
                colsum[j] += tv;
                colsq[j] = fmaf(tv, tv, colsq[j]);
            }
        }
    }
    const int bb = blockIdx.y >> 3;   // batch index (128 rows/block, 8 blocks/batch)
#pragma unroll
    for (int j = 0; j < NJ; ++j) {
        float s = colsum[j];
        float q = colsq[j];
        s += __shfl_xor(s, 16); s += __shfl_xor(s, 32);
        q += __shfl_xor(q, 16); q += __shfl_xor(q, 32);
        if (lane < 16) {
            const int c = col0 + wcol + j * 16 + lm;
            atomicAdd(&csum[c], s);
            atomicAdd(&csq[c], q);
            if (EPI == 0) atomicAdd(&gsum[bb * NS + c], s);
        }
    }
}

// ---------------- K4: dynamic kernel MLP + fused BN1 stats ----------------
__global__ __launch_bounds__(1024) void dynmlp_kernel(const float* __restrict__ chsum1,
                                                      const float* __restrict__ chsq1,
                                                      const float* __restrict__ gapsum,
                                                      const float* __restrict__ g1,
                                                      const float* __restrict__ be1,
                                                      const float* __restrict__ aw1,
                                                      const float* __restrict__ ab1,
                                                      const float* __restrict__ aw2,
                                                      const float* __restrict__ ab2,
                                                      float* __restrict__ scale1,
                                                      float* __restrict__ shift1,
                                                      float* __restrict__ kw) {
    const int b = blockIdx.x;
    const int t = threadIdx.x;
    const int wave = t >> 6, lane = t & 63;
    __shared__ float g[1024];
    __shared__ float h1[128];
    __shared__ float logits[12];
    {
        const float m = chsum1[t] * (1.0f / (float)M);
        const float var = chsq1[t] * (1.0f / (float)M) - m * m;
        const float rstd = rsqrtf(var + EPS);
        const float sc = rstd * g1[t];
        const float sh = be1[t] - m * sc;
        if (b == 0) { scale1[t] = sc; shift1[t] = sh; }
        g[t] = gapsum[b * C + t] * (1.0f / (float)P) * sc + sh;
    }
    __syncthreads();
    // layer1: 128 units, one per (wave, k)
#pragma unroll
    for (int k = 0; k < 8; ++k) {
        const int u = wave * 8 + k;
        const float4* wr = (const float4*)(aw1 + (size_t)u * C);
        float s = 0.f;
#pragma unroll
        for (int ch = 0; ch < 4; ++ch) {
            const float4 wv = wr[lane + 64 * ch];
            const float4 sv = *(const float4*)(g + 4 * lane + 256 * ch);
            s += wv.x * sv.x + wv.y * sv.y + wv.z * sv.z + wv.w * sv.w;
        }
#pragma unroll
        for (int off = 1; off < 64; off <<= 1) s += __shfl_xor(s, off);
        if (lane == 0) h1[u] = fmaxf(s + ab1[u], 0.f);
    }
    __syncthreads();
    // layer2: 9 logits, one wave each
    if (wave < 9) {
        float s = aw2[wave * 128 + lane] * h1[lane]
                + aw2[wave * 128 + 64 + lane] * h1[64 + lane];
#pragma unroll
        for (int off = 1; off < 64; off <<= 1) s += __shfl_xor(s, off);
        if (lane == 0) logits[wave] = s + ab2[wave];
    }
    __syncthreads();
    if (t == 0) {
        float mx = logits[0];
        for (int i = 1; i < 9; ++i) mx = fmaxf(mx, logits[i]);
        float e[9], den = 0.f;
        for (int i = 0; i < 9; ++i) { e[i] = expf(logits[i] - mx); den += e[i]; }
        const float inv = 1.0f / den;
        for (int i = 0; i < 9; ++i) kw[b * 9 + i] = e[i] * inv;
    }
}

// ---------------- K5: dyn depthwise conv, sliding window, 2 channels/thread ----------------
// partials stored transposed: p*[c*256 + b*32 + h]
__global__ __launch_bounds__(256) void dwconv_kernel(const u16* __restrict__ t1b,
                                                     const float* __restrict__ scale1,
                                                     const float* __restrict__ shift1,
                                                     const float* __restrict__ kw,
                                                     u16* __restrict__ t2b,
                                                     float* __restrict__ psum,
                                                     float* __restrict__ psq,
                                                     float* __restrict__ pmax,
                                                     float* __restrict__ pmin) {
    const int b = blockIdx.y >> 5;
    const int h = blockIdx.y & 31;
    const int c0 = (blockIdx.x * 256 + threadIdx.x) * 2;
    float k[9];
#pragma unroll
    for (int i = 0; i < 9; ++i) k[i] = kw[b * 9 + i];
    const float sc0 = scale1[c0],     sh0 = shift1[c0];
    const float sc1 = scale1[c0 + 1], sh1 = shift1[c0 + 1];
    const u16* base = t1b + (size_t)b * P * C + c0;
    const bool rok[3] = { h > 0, true, h < H - 1 };

    float2 win[3][3];
    const float2 z = {0.f, 0.f};
#pragma unroll
    for (int ri = 0; ri < 3; ++ri) {
        win[ri][0] = z;
#pragma unroll
        for (int ci = 1; ci < 3; ++ci) {
            if (rok[ri]) {
                const u32 v = *(const u32*)(base + ((size_t)((h + ri - 1) * W + (ci - 1))) * C);
                float2 r;
                r.x = fmaf(bf2f((u16)(v & 0xffff)), sc0, sh0);
                r.y = fmaf(bf2f((u16)(v >> 16)),    sc1, sh1);
                win[ri][ci] = r;
            } else win[ri][ci] = z;
        }
    }

    float s0 = 0.f, q0 = 0.f, mx0 = -INFINITY, mn0 = INFINITY;
    float s1 = 0.f, q1 = 0.f, mx1 = -INFINITY, mn1 = INFINITY;
    for (int w = 0; w < W; ++w) {
        float a0 = 0.f, a1 = 0.f;
#pragma unroll
        for (int ri = 0; ri < 3; ++ri)
#pragma unroll
            for (int ci = 0; ci < 3; ++ci) {
                a0 = fmaf(k[ri * 3 + ci], win[ri][ci].x, a0);
                a1 = fmaf(k[ri * 3 + ci], win[ri][ci].y, a1);
            }
        const float y0 = gelu_exact(a0);
        const float y1 = gelu_exact(a1);
        *(u32*)(t2b + ((size_t)b * P + h * W + w) * C + c0) =
            ((u32)f2bf(y0)) | ((u32)f2bf(y1) << 16);
        s0 += y0; q0 = fmaf(y0, y0, q0); mx0 = fmaxf(mx0, y0); mn0 = fminf(mn0, y0);
        s1 += y1; q1 = fmaf(y1, y1, q1); mx1 = fmaxf(mx1, y1); mn1 = fminf(mn1, y1);
        // slide window
        if (w < W - 1) {
#pragma unroll
            for (int ri = 0; ri < 3; ++ri) {
                win[ri][0] = win[ri][1];
                win[ri][1] = win[ri][2];
                if (rok[ri] && (w + 2 < W)) {
                    const u32 v = *(const u32*)(base + ((size_t)((h + ri - 1) * W + (w + 2))) * C);
                    float2 r;
                    r.x = fmaf(bf2f((u16)(v & 0xffff)), sc0, sh0);
                    r.y = fmaf(bf2f((u16)(v >> 16)),    sc1, sh1);
                    win[ri][2] = r;
                } else win[ri][2] = z;
            }
        }
    }
    const int idx = b * 32 + h;
    psum[c0 * 256 + idx] = s0;  psum[(c0 + 1) * 256 + idx] = s1;
    psq [c0 * 256 + idx] = q0;  psq [(c0 + 1) * 256 + idx] = q1;
    pmax[c0 * 256 + idx] = mx0; pmax[(c0 + 1) * 256 + idx] = mx1;
    pmin[c0 * 256 + idx] = mn0; pmin[(c0 + 1) * 256 + idx] = mn1;
}

// ---------------- K7: BN2 stats + per-(b,c) avg/max (one block per channel) ----------------
__global__ __launch_bounds__(256) void stats2_kernel(const float* __restrict__ psum,
                                                     const float* __restrict__ psq,
                                                     const float* __restrict__ pmax,
                                                     const float* __restrict__ pmin,
                                                     const float* __restrict__ g2,
                                                     const float* __restrict__ be2,
                                                     float* __restrict__ scale2,
                                                     float* __restrict__ shift2,
                                                     float* __restrict__ avgbn,
                                                     float* __restrict__ mxbn) {
    const int c = blockIdx.x;
    const int t = threadIdx.x;              // row index (b*32+h)
    const int base = c * 256 + t;
    float s  = psum[base];
    float q  = psq[base];
    float mx = pmax[base];
    float mn = pmin[base];
    // segmented reduce within 32-lane groups (= one batch's 32 h-partials)
#pragma unroll
    for (int off = 1; off < 32; off <<= 1) {
        s += __shfl_xor(s, off);
        q += __shfl_xor(q, off);
        mx = fmaxf(mx, __shfl_xor(mx, off));
        mn = fminf(mn, __shfl_xor(mn, off));
    }
    __shared__ float bs[8], bq[8], bmx[8], bmn[8];
    __shared__ float sc_sh[2];
    if ((t & 31) == 0) {
        const int b = t >> 5;
        bs[b] = s; bq[b] = q; bmx[b] = mx; bmn[b] = mn;
    }
    __syncthreads();
    if (t == 0) {
        float S = 0.f, Q = 0.f;
#pragma unroll
        for (int b = 0; b < 8; ++b) { S += bs[b]; Q += bq[b]; }
        const float m = S * (1.0f / (float)M);
        const float var = Q * (1.0f / (float)M) - m * m;
        const float rstd = rsqrtf(var + EPS);
        const float sc = rstd * g2[c];
        const float sh = be2[c] - m * sc;
        scale2[c] = sc;
        shift2[c] = sh;
        sc_sh[0] = sc; sc_sh[1] = sh;
    }
    __syncthreads();
    if (t < 8) {
        const float sc = sc_sh[0], sh = sc_sh[1];
        avgbn[t * C + c] = bs[t] * (1.0f / (float)P) * sc + sh;
        mxbn[t * C + c] = (sc >= 0.f ? bmx[t] : bmn[t]) * sc + sh;
    }
}

// ---------------- K8: channel attention (wave-parallel dots) ----------------
__global__ __launch_bounds__(1024) void chatt_kernel(const float* __restrict__ avgbn,
                                                     const float* __restrict__ mxbn,
                                                     const float* __restrict__ caw1,
                                                     const float* __restrict__ caw2,
                                                     float* __restrict__ s_att) {
    const int b = blockIdx.x;
    const int t = threadIdx.x;
    const int wave = t >> 6, lane = t & 63;
    __shared__ float la[1024], lx[1024], ha[64], hm[64];
    la[t] = avgbn[b * C + t];
    lx[t] = mxbn[b * C + t];
    __syncthreads();
    // layer1: 128 units (64 avg + 64 max), one per (wave, k)
#pragma unroll
    for (int k = 0; k < 8; ++k) {
        const int u = wave * 8 + k;
        const int row = u & 63;
        const float* src = (u < 64) ? la : lx;
        const float4* wr = (const float4*)(caw1 + (size_t)row * C);
        float s = 0.f;
#pragma unroll
        for (int ch = 0; ch < 4; ++ch) {
            const float4 wv = wr[lane + 64 * ch];
            const float4 sv = *(const float4*)(src + 4 * lane + 256 * ch);
            s += wv.x * sv.x + wv.y * sv.y + wv.z * sv.z + wv.w * sv.w;
        }
#pragma unroll
        for (int off = 1; off < 64; off <<= 1) s += __shfl_xor(s, off);
        if (lane == 0) {
            s = fmaxf(s, 0.f);
            if (u < 64) ha[row] = s; else hm[row] = s;
        }
    }
    __syncthreads();
    // layer2: 1024 outputs, one per thread (64-length dot from LDS)
    {
        const float4* w2 = (const float4*)(caw2 + (size_t)t * 64);
        float s = 0.f;
#pragma unroll
        for (int j = 0; j < 16; ++j) {
            const float4 wv = w2[j];
            s += wv.x * (ha[j * 4 + 0] + hm[j * 4 + 0]);
            s += wv.y * (ha[j * 4 + 1] + hm[j * 4 + 1]);
            s += wv.z * (ha[j * 4 + 2] + hm[j * 4 + 2]);
            s += wv.w * (ha[j * 4 + 3] + hm[j * 4 + 3]);
        }
        s_att[b * C + t] = 1.0f / (1.0f + expf(-s));
    }
}

// ---------------- K9: y = s_att*bn2(t2) -> bf16 yb + per-row avg/max ----------------
__global__ __launch_bounds__(256) void yq_kernel(const u16* __restrict__ t2b,
                                                 const float* __restrict__ scale2,
                                                 const float* __restrict__ shift2,
                                                 const float* __restrict__ s_att,
                                                 u16* __restrict__ yb,
                                                 float* __restrict__ avg_o,
                                                 float* __restrict__ max_o) {
    const int row = blockIdx.x;       // b*P + p
    const int b = row >> 10;
    const int t = threadIdx.x;
    const int c0 = t * 4;
    const uint2 vv = *(const uint2*)(t2b + (size_t)row * C + c0);
    const float v0 = bf2f((u16)(vv.x & 0xffff));
    const float v1 = bf2f((u16)(vv.x >> 16));
    const float v2 = bf2f((u16)(vv.y & 0xffff));
    const float v3 = bf2f((u16)(vv.y >> 16));
    const float4 sc = *(const float4*)(scale2 + c0);
    const float4 sh = *(const float4*)(shift2 + c0);
    const float4 sa = *(const float4*)(s_att + (size_t)b * C + c0);
    const float y0 = fmaf(v0, sc.x, sh.x) * sa.x;
    const float y1 = fmaf(v1, sc.y, sh.y) * sa.y;
    const float y2 = fmaf(v2, sc.z, sh.z) * sa.z;
    const float y3 = fmaf(v3, sc.w, sh.w) * sa.w;
    uint2 o;
    o.x = ((u32)f2bf(y0)) | ((u32)f2bf(y1) << 16);
    o.y = ((u32)f2bf(y2)) | ((u32)f2bf(y3) << 16);
    *(uint2*)(yb + (size_t)row * C + c0) = o;
    float s = (y0 + y1) + (y2 + y3);
    float mx = fmaxf(fmaxf(y0, y1), fmaxf(y2, y3));
#pragma unroll
    for (int off = 32; off > 0; off >>= 1) {
        s += __shfl_down(s, off);
        mx = fmaxf(mx, __shfl_down(mx, off));
    }
    __shared__ float ss[4], sm[4];
    const int wave = t >> 6, lane = t & 63;
    if (lane == 0) { ss[wave] = s; sm[wave] = mx; }
    __syncthreads();
    if (t == 0) {
        const float S = ss[0] + ss[1] + ss[2] + ss[3];
        const float Mx = fmaxf(fmaxf(sm[0], sm[1]), fmaxf(sm[2], sm[3]));
        avg_o[row] = S * (1.0f / (float)C);
        max_o[row] = Mx;
    }
}

// ---------------- K10: 7x7 spatial conv + sigmoid (1 pixel/thread) ----------------
__global__ __launch_bounds__(1024) void spconv_kernel(const float* __restrict__ avg_o,
                                                      const float* __restrict__ max_o,
                                                      const float* __restrict__ sw,
                                                      const float* __restrict__ sb,
                                                      float* __restrict__ sp) {
    const int b = blockIdx.x;
    const int t = threadIdx.x;
    __shared__ float pa[P], pm[P], wsh[98];
    pa[t] = avg_o[b * P + t];
    pm[t] = max_o[b * P + t];
    if (t < 98) wsh[t] = sw[t];
    const float sbv = sb[0];
    __syncthreads();
    const int h = t >> 5, w = t & 31;
    float acc = sbv;
#pragma unroll
    for (int i = 0; i < 7; ++i) {
        const int hh = h + i - 3;
        if (hh < 0 || hh >= H) continue;
#pragma unroll
        for (int j = 0; j < 7; ++j) {
            const int ww = w + j - 3;
            if (ww < 0 || ww >= W) continue;
            const int pidx = hh * W + ww;
            acc = fmaf(wsh[i * 7 + j], pa[pidx], acc);
            acc = fmaf(wsh[49 + i * 7 + j], pm[pidx], acc);
        }
    }
    sp[b * P + t] = 1.0f / (1.0f + expf(-acc));
}

// ---------------- K15: final residual add + fused BN3 stats ----------------
__global__ __launch_bounds__(256) void final_kernel(const float* __restrict__ x,
                                                    const float* __restrict__ pre,
                                                    const float* __restrict__ chsum3,
                                                    const float* __restrict__ chsq3,
                                                    const float* __restrict__ g3,
                                                    const float* __restrict__ be3,
                                                    float* __restrict__ out) {
    __shared__ float lsc[256], lsh[256];
    const int t = threadIdx.x;
    {
        const float m = chsum3[t] * (1.0f / (float)M);
        const float var = chsq3[t] * (1.0f / (float)M) - m * m;
        const float rstd = rsqrtf(var + EPS);
        const float sc = rstd * g3[t];
        lsc[t] = sc;
        lsh[t] = be3[t] - m * sc;
    }
    __syncthreads();
    const int i = blockIdx.x * 256 + t;   // float4 index
    const int e = i * 4;
    const int d = e & 255;
    const float4 xv = *(const float4*)(x + e);
    const float4 pv = *(const float4*)(pre + e);
    const float4 sc = *(const float4*)(lsc + d);
    const float4 sh = *(const float4*)(lsh + d);
    float4 o;
    o.x = xv.x + fmaf(pv.x, sc.x, sh.x);
    o.y = xv.y + fmaf(pv.y, sc.y, sh.y);
    o.z = xv.z + fmaf(pv.z, sc.z, sh.z);
    o.w = xv.w + fmaf(pv.w, sc.w, sh.w);
    *(float4*)(out + e) = o;
}

extern "C" void kernel_launch(void* const* d_in, const int* in_sizes, int n_in,
                              void* d_out, int out_size, void* d_ws, size_t ws_size,
                              hipStream_t stream) {
    const float* x    = (const float*)d_in[0];
    const float* w1   = (const float*)d_in[1];
    const float* b1   = (const float*)d_in[2];
    const float* g1   = (const float*)d_in[3];
    const float* be1  = (const float*)d_in[4];
    const float* aw1  = (const float*)d_in[5];
    const float* ab1  = (const float*)d_in[6];
    const float* aw2  = (const float*)d_in[7];
    const float* ab2  = (const float*)d_in[8];
    const float* g2   = (const float*)d_in[9];
    const float* be2  = (const float*)d_in[10];
    const float* caw1 = (const float*)d_in[11];
    const float* caw2 = (const float*)d_in[12];
    const float* pw   = (const float*)d_in[13];
    const float* pb   = (const float*)d_in[14];
    const float* g3   = (const float*)d_in[15];
    const float* be3  = (const float*)d_in[16];
    const float* sw   = (const float*)d_in[17];
    const float* sb   = (const float*)d_in[18];
    float* out = (float*)d_out;
    float* ws = (float*)d_ws;

    // zero atomic accumulators
    hipMemsetAsync(ws, 0, WS_ACC_COUNT * sizeof(float), stream);

    float* chsum1  = ws + WS_CHSUM1;
    float* chsq1   = ws + WS_CHSQ1;
    float* gapsum  = ws + WS_GAPSUM;
    float* chsum3  = ws + WS_CHSUM3;
    float* chsq3   = ws + WS_CHSQ3;
    float* scale1  = ws + WS_SCALE1;
    float* shift1  = ws + WS_SHIFT1;
    float* kw      = ws + WS_KW;
    float* scale2  = ws + WS_SCALE2;
    float* shift2  = ws + WS_SHIFT2;
    float* avgbn   = ws + WS_AVGBN;
    float* mxbn    = ws + WS_MXBN;
    float* s_att   = ws + WS_SATT;
    float* avg_o   = ws + WS_AVGO;
    float* max_o   = ws + WS_MAXO;
    float* sp      = ws + WS_SP;
    float* psum2   = ws + WS_PSUM2;
    float* psq2    = ws + WS_PSQ2;
    float* pmax2   = ws + WS_PMAX2;
    float* pmin2   = ws + WS_PMIN2;
    float* pre     = ws + WS_PRE;
    u16* t1b = (u16*)(ws + WS_T1B);
    u16* t2b = (u16*)(ws + WS_T2B);
    u16* xb  = (u16*)(ws + WS_XB);
    u16* w1b = (u16*)(ws + WS_W1B);
    u16* pwb = (u16*)(ws + WS_PWB);
    u16* yb  = (u16*)(ws + WS_YB);

    // K0: all casts in one launch (655360 float4 units)
    cvt_all_kernel<<<dim3(2560), 256, 0, stream>>>(x, w1, pw, xb, w1b, pwb);
    // K1: expand GEMM (bf16 MFMA) + bias + GELU -> bf16 t1, fused BN1 partial stats
    mfma_gemm_kernel<256, 0, C, 128><<<dim3(C / 128, M / 128), 256, 0, stream>>>(
        xb, w1b, b1, nullptr, t1b, chsum1, chsq1, gapsum);
    // K4: BN1 stats + gap + dynamic kernel weights (fused)
    dynmlp_kernel<<<dim3(B), 1024, 0, stream>>>(chsum1, chsq1, gapsum, g1, be1,
                                                aw1, ab1, aw2, ab2, scale1, shift1, kw);
    // K5: depthwise conv + GELU -> bf16 t2, fused BN2 partials (transposed layout)
    dwconv_kernel<<<dim3(C / 512, B * H), 256, 0, stream>>>(t1b, scale1, shift1, kw, t2b,
                                                            psum2, psq2, pmax2, pmin2);
    // K7: BN2 stats + per-(b,c) avg/max — one block per channel (1024 blocks)
    stats2_kernel<<<dim3(C), 256, 0, stream>>>(psum2, psq2, pmax2, pmin2, g2, be2,
                                               scale2, shift2, avgbn, mxbn);
    // K8: channel attention
    chatt_kernel<<<dim3(B), 1024, 0, stream>>>(avgbn, mxbn, caw1, caw2, s_att);
    // K9: y quantize + spatial stats
    yq_kernel<<<dim3(M), 256, 0, stream>>>(t2b, scale2, shift2, s_att, yb, avg_o, max_o);
    // K10: 7x7 conv + sigmoid
    spconv_kernel<<<dim3(B), 1024, 0, stream>>>(avg_o, max_o, sw, sb, sp);
    // K12: project GEMM (bf16 MFMA, 128x64 tile) + sp/bias epilogue -> fp32 pre, fused BN3 stats
    mfma_gemm_kernel<1024, 1, D, 64><<<dim3(D / 64, M / 128), 256, 0, stream>>>(
        yb, pwb, pb, sp, pre, chsum3, chsq3, nullptr);
    // K15: BN3 stats + final residual add (fused)
    final_kernel<<<dim3((M * D / 4) / 256), 256, 0, stream>>>(x, pre, chsum3, chsq3, g3, be3, out);
}

// Round 7
// 218.915 us; speedup vs baseline: 1.3703x; 1.0215x over previous
//
#include <hip/hip_runtime.h>
#include <math.h>

// Problem constants
constexpr int B = 8;
constexpr int D = 256;     // model dim
constexpr int C = 1024;    // expanded channels
constexpr int H = 32, W = 32;
constexpr int P = H * W;            // 1024 spatial positions
constexpr int M = B * P;            // 8192 rows
constexpr float EPS = 1e-5f;

typedef unsigned short u16;
typedef unsigned int u32;
typedef __attribute__((ext_vector_type(8))) short short8;
typedef __attribute__((ext_vector_type(4))) float floatx4;

// ---------------- workspace layout (in floats) ----------------
constexpr size_t WS_CHSUM1 = 0;                  // 1024
constexpr size_t WS_CHSQ1  = 1024;               // 1024
constexpr size_t WS_GAPSUM = 2048;               // 8192
constexpr size_t WS_CHSUM3 = 10240;              // 256
constexpr size_t WS_CHSQ3  = 10496;              // 256
constexpr size_t WS_ACC_COUNT = 10752;
constexpr size_t WS_SCALE1 = 11264;              // 1024
constexpr size_t WS_SHIFT1 = 12288;              // 1024
constexpr size_t WS_KW     = 21504;              // 256 (72 used)
constexpr size_t WS_SCALE2 = 21760;              // 1024
constexpr size_t WS_SHIFT2 = 22784;              // 1024
constexpr size_t WS_AVGBN  = 23808;              // 8192
constexpr size_t WS_MXBN   = 32000;              // 8192
constexpr size_t WS_SATT   = 40192;              // 8192
constexpr size_t WS_AVGO   = 48384;              // 8192
constexpr size_t WS_MAXO   = 56576;              // 8192
constexpr size_t WS_SP     = 64768;              // 8192
constexpr size_t WS_PSUM2  = 73728;              // 262144  (partials [C][256], transposed)
constexpr size_t WS_PSQ2   = 335872;             // 262144
constexpr size_t WS_PMAX2  = 598016;             // 262144
constexpr size_t WS_PMIN2  = 860160;             // 262144
constexpr size_t WS_PRE    = 1122304;            // 2097152
constexpr size_t WS_T1B    = 3219456;            // bf16 t1
constexpr size_t WS_T2B    = 7413760;            // bf16 t2
constexpr size_t WS_XB     = 11608064;           // bf16 x
constexpr size_t WS_W1B    = 12656640;
constexpr size_t WS_PWB    = 12787712;
constexpr size_t WS_YB     = 12918784;           // bf16 y
// total = 17113088 floats = 68.5 MB

__device__ __forceinline__ float gelu_exact(float v) {
    return 0.5f * v * (1.0f + erff(v * 0.70710678118654752440f));
}

__device__ __forceinline__ u16 f2bf(float f) {
    u32 u = __float_as_uint(f);
    u += 0x7fff + ((u >> 16) & 1);   // round-to-nearest-even
    return (u16)(u >> 16);
}

__device__ __forceinline__ float bf2f(u16 v) {
    return __uint_as_float(((u32)v) << 16);
}

// ---------------- K0: fused cast fp32 -> bf16 for x, w1, pw ----------------
__global__ __launch_bounds__(256) void cvt_all_kernel(const float* __restrict__ x,
                                                      const float* __restrict__ w1,
                                                      const float* __restrict__ pw,
                                                      u16* __restrict__ xb,
                                                      u16* __restrict__ w1b,
                                                      u16* __restrict__ pwb) {
    const int i = blockIdx.x * 256 + threadIdx.x;
    const float* src;
    u16* dst;
    int off;
    if (i < 524288)      { src = x;  dst = xb;  off = i; }
    else if (i < 589824) { src = w1; dst = w1b; off = i - 524288; }
    else                 { src = pw; dst = pwb; off = i - 589824; }
    const float4 v = *(const float4*)(src + (size_t)off * 4);
    uint2 o;
    o.x = ((u32)f2bf(v.x)) | ((u32)f2bf(v.y) << 16);
    o.y = ((u32)f2bf(v.z)) | ((u32)f2bf(v.w) << 16);
    *(uint2*)(dst + (size_t)off * 4) = o;
}

// ---------------- MFMA bf16 GEMM + fused epilogue + fused column stats ----------------
// MBxNB tile, BK=32, global_load_lds width=16, 4 waves of (MB/2)x(NB/2).
// EPI 0 (gemm1): t = gelu(acc + bias[col]); store bf16 via LDS-staged coalesced writes;
//                stats -> sum/sq/gsum[b*NS+col]
// EPI 1 (gemm2): t = rowscale[row]*acc + bias[col]; store fp32 direct; stats -> sum/sq
// Dynamic LDS: EPI0: max(MB*32+NB*32, MB*NB) u16;  EPI1: (MB*32+NB*32) u16
template<int KD, int EPI, int NS, int MB, int NB>
__global__ __launch_bounds__(256) void mfma_gemm_kernel(
    const u16* __restrict__ A,
    const u16* __restrict__ Bw,
    const float* __restrict__ bias,
    const float* __restrict__ rowscale,
    void* __restrict__ outv,
    float* __restrict__ csum,
    float* __restrict__ csq,
    float* __restrict__ gsum)
{
    constexpr int MI = MB / 32;               // acc row-blocks per wave
    constexpr int NJ = NB / 32;               // acc col-blocks per wave
    extern __shared__ u16 smem[];
    u16* As = smem;                            // MB*32
    u16* Bs = smem + MB * 32;                  // NB*32
    const int t = threadIdx.x;
    const int lane = t & 63;
    const int row0 = blockIdx.y * MB;
    const int col0 = blockIdx.x * NB;
    const int wv = t >> 6;
    const int wrow = (wv >> 1) * (MB / 2);
    const int wcol = (wv & 1) * (NB / 2);
    const int lm = lane & 15;
    const int lk8 = (lane >> 4) * 8;

    const int srow = t >> 2;                   // 0..63
    const int scol = (t & 3) * 8;

    const u16* gA0 = A + (size_t)(row0 + srow) * KD + scol;
    const u16* gA1 = A + (size_t)(row0 + 64 + srow) * KD + scol;
    const u16* gB0 = Bw + (size_t)(col0 + srow) * KD + scol;

    const floatx4 zero = {0.f, 0.f, 0.f, 0.f};
    floatx4 acc[MI][NJ];
#pragma unroll
    for (int i = 0; i < MI; ++i)
#pragma unroll
        for (int j = 0; j < NJ; ++j) acc[i][j] = zero;

    for (int k0 = 0; k0 < KD; k0 += 32) {
        __builtin_amdgcn_global_load_lds(
            (const __attribute__((address_space(1))) void*)(gA0 + k0),
            (__attribute__((address_space(3))) void*)(As + t * 8), 16, 0, 0);
        if (MB == 128)
            __builtin_amdgcn_global_load_lds(
                (const __attribute__((address_space(1))) void*)(gA1 + k0),
                (__attribute__((address_space(3))) void*)(As + 2048 + t * 8), 16, 0, 0);
        __builtin_amdgcn_global_load_lds(
            (const __attribute__((address_space(1))) void*)(gB0 + k0),
            (__attribute__((address_space(3))) void*)(Bs + t * 8), 16, 0, 0);
        __syncthreads();
        short8 af[MI], bf[NJ];
#pragma unroll
        for (int i = 0; i < MI; ++i)
            af[i] = *(const short8*)(As + (wrow + i * 16 + lm) * 32 + lk8);
#pragma unroll
        for (int j = 0; j < NJ; ++j)
            bf[j] = *(const short8*)(Bs + (wcol + j * 16 + lm) * 32 + lk8);
#pragma unroll
        for (int i = 0; i < MI; ++i)
#pragma unroll
            for (int j = 0; j < NJ; ++j)
                acc[i][j] = __builtin_amdgcn_mfma_f32_16x16x32_bf16(af[i], bf[j], acc[i][j], 0, 0, 0);
        __syncthreads();
    }

    // C/D layout: col = lane&15, row = (lane>>4)*4 + reg
    float colsum[NJ], colsq[NJ];
#pragma unroll
    for (int j = 0; j < NJ; ++j) { colsum[j] = 0.f; colsq[j] = 0.f; }

    if (EPI == 0) {
        // compute + stage bf16 tile in LDS (MB x NB u16), then coalesced global stores
        u16* Cs = smem;
#pragma unroll
        for (int i = 0; i < MI; ++i) {
#pragma unroll
            for (int r = 0; r < 4; ++r) {
                const int lrow = wrow + i * 16 + (lane >> 4) * 4 + r;
#pragma unroll
                for (int j = 0; j < NJ; ++j) {
                    const int lcol = wcol + j * 16 + lm;
                    const float tv = gelu_exact(acc[i][j][r] + bias[col0 + lcol]);
                    Cs[lrow * NB + lcol] = f2bf(tv);
                    colsum[j] += tv;
                    colsq[j] = fmaf(tv, tv, colsq[j]);
                }
            }
        }
        __syncthreads();
        // readback: thread t covers 64 B of a row (MB rows x NB u16; NB=64 -> 2 threads/row)
        const int rr = t >> 1;
        const int hh = (t & 1) * 32;            // u16 offset within row
        u16* outp = (u16*)outv + (size_t)(row0 + rr) * NS + col0 + hh;
#pragma unroll
        for (int k = 0; k < 4; ++k) {
            *(uint4*)(outp + k * 8) = *(const uint4*)(Cs + rr * NB + hh + k * 8);
        }
    } else {
#pragma unroll
        for (int i = 0; i < MI; ++i) {
#pragma unroll
            for (int r = 0; r < 4; ++r) {
                const int grow = row0 + wrow + i * 16 + (lane >> 4) * 4 + r;
                const float rs = rowscale[grow];
#pragma unroll
                for (int j = 0; j < NJ; ++j) {
                    const int gcol = col0 + wcol + j * 16 + lm;
                    const float tv = rs * acc[i][j][r] + bias[gcol];
                    ((float*)outv)[(size_t)grow * NS + gcol] = tv;
                    colsum[j] += tv;
                    colsq[j] = fmaf(tv, tv, colsq[j]);
                }
            }
        }
    }

    const int bb = (blockIdx.y * MB) >> 10;   // batch index
#pragma unroll
    for (int j = 0; j < NJ; ++j) {
        float s = colsum[j];
        float q = colsq[j];
        s += __shfl_xor(s, 16); s += __shfl_xor(s, 32);
        q += __shfl_xor(q, 16); q += __shfl_xor(q, 32);
        if (lane < 16) {
            const int c = col0 + wcol + j * 16 + lm;
            atomicAdd(&csum[c], s);
            atomicAdd(&csq[c], q);
            if (EPI == 0) atomicAdd(&gsum[bb * NS + c], s);
        }
    }
}

// ---------------- K4: dynamic kernel MLP + fused BN1 stats ----------------
__global__ __launch_bounds__(1024) void dynmlp_kernel(const float* __restrict__ chsum1,
                                                      const float* __restrict__ chsq1,
                                                      const float* __restrict__ gapsum,
                                                      const float* __restrict__ g1,
                                                      const float* __restrict__ be1,
                                                      const float* __restrict__ aw1,
                                                      const float* __restrict__ ab1,
                                                      const float* __restrict__ aw2,
                                                      const float* __restrict__ ab2,
                                                      float* __restrict__ scale1,
                                                      float* __restrict__ shift1,
                                                      float* __restrict__ kw) {
    const int b = blockIdx.x;
    const int t = threadIdx.x;
    const int wave = t >> 6, lane = t & 63;
    __shared__ float g[1024];
    __shared__ float h1[128];
    __shared__ float logits[12];
    {
        const float m = chsum1[t] * (1.0f / (float)M);
        const float var = chsq1[t] * (1.0f / (float)M) - m * m;
        const float rstd = rsqrtf(var + EPS);
        const float sc = rstd * g1[t];
        const float sh = be1[t] - m * sc;
        if (b == 0) { scale1[t] = sc; shift1[t] = sh; }
        g[t] = gapsum[b * C + t] * (1.0f / (float)P) * sc + sh;
    }
    __syncthreads();
#pragma unroll
    for (int k = 0; k < 8; ++k) {
        const int u = wave * 8 + k;
        const float4* wr = (const float4*)(aw1 + (size_t)u * C);
        float s = 0.f;
#pragma unroll
        for (int ch = 0; ch < 4; ++ch) {
            const float4 wv = wr[lane + 64 * ch];
            const float4 sv = *(const float4*)(g + 4 * lane + 256 * ch);
            s += wv.x * sv.x + wv.y * sv.y + wv.z * sv.z + wv.w * sv.w;
        }
#pragma unroll
        for (int off = 1; off < 64; off <<= 1) s += __shfl_xor(s, off);
        if (lane == 0) h1[u] = fmaxf(s + ab1[u], 0.f);
    }
    __syncthreads();
    if (wave < 9) {
        float s = aw2[wave * 128 + lane] * h1[lane]
                + aw2[wave * 128 + 64 + lane] * h1[64 + lane];
#pragma unroll
        for (int off = 1; off < 64; off <<= 1) s += __shfl_xor(s, off);
        if (lane == 0) logits[wave] = s + ab2[wave];
    }
    __syncthreads();
    if (t == 0) {
        float mx = logits[0];
        for (int i = 1; i < 9; ++i) mx = fmaxf(mx, logits[i]);
        float e[9], den = 0.f;
        for (int i = 0; i < 9; ++i) { e[i] = expf(logits[i] - mx); den += e[i]; }
        const float inv = 1.0f / den;
        for (int i = 0; i < 9; ++i) kw[b * 9 + i] = e[i] * inv;
    }
}

// ---------------- K5: dyn depthwise conv, sliding window, 2 channels/thread ----------------
__global__ __launch_bounds__(256) void dwconv_kernel(const u16* __restrict__ t1b,
                                                     const float* __restrict__ scale1,
                                                     const float* __restrict__ shift1,
                                                     const float* __restrict__ kw,
                                                     u16* __restrict__ t2b,
                                                     float* __restrict__ psum,
                                                     float* __restrict__ psq,
                                                     float* __restrict__ pmax,
                                                     float* __restrict__ pmin) {
    const int b = blockIdx.y >> 5;
    const int h = blockIdx.y & 31;
    const int c0 = (blockIdx.x * 256 + threadIdx.x) * 2;
    float k[9];
#pragma unroll
    for (int i = 0; i < 9; ++i) k[i] = kw[b * 9 + i];
    const float sc0 = scale1[c0],     sh0 = shift1[c0];
    const float sc1 = scale1[c0 + 1], sh1 = shift1[c0 + 1];
    const u16* base = t1b + (size_t)b * P * C + c0;
    const bool rok[3] = { h > 0, true, h < H - 1 };

    float2 win[3][3];
    const float2 z = {0.f, 0.f};
#pragma unroll
    for (int ri = 0; ri < 3; ++ri) {
        win[ri][0] = z;
#pragma unroll
        for (int ci = 1; ci < 3; ++ci) {
            if (rok[ri]) {
                const u32 v = *(const u32*)(base + ((size_t)((h + ri - 1) * W + (ci - 1))) * C);
                float2 r;
                r.x = fmaf(bf2f((u16)(v & 0xffff)), sc0, sh0);
                r.y = fmaf(bf2f((u16)(v >> 16)),    sc1, sh1);
                win[ri][ci] = r;
            } else win[ri][ci] = z;
        }
    }

    float s0 = 0.f, q0 = 0.f, mx0 = -INFINITY, mn0 = INFINITY;
    float s1 = 0.f, q1 = 0.f, mx1 = -INFINITY, mn1 = INFINITY;
    for (int w = 0; w < W; ++w) {
        float a0 = 0.f, a1 = 0.f;
#pragma unroll
        for (int ri = 0; ri < 3; ++ri)
#pragma unroll
            for (int ci = 0; ci < 3; ++ci) {
                a0 = fmaf(k[ri * 3 + ci], win[ri][ci].x, a0);
                a1 = fmaf(k[ri * 3 + ci], win[ri][ci].y, a1);
            }
        const float y0 = gelu_exact(a0);
        const float y1 = gelu_exact(a1);
        *(u32*)(t2b + ((size_t)b * P + h * W + w) * C + c0) =
            ((u32)f2bf(y0)) | ((u32)f2bf(y1) << 16);
        s0 += y0; q0 = fmaf(y0, y0, q0); mx0 = fmaxf(mx0, y0); mn0 = fminf(mn0, y0);
        s1 += y1; q1 = fmaf(y1, y1, q1); mx1 = fmaxf(mx1, y1); mn1 = fminf(mn1, y1);
        if (w < W - 1) {
#pragma unroll
            for (int ri = 0; ri < 3; ++ri) {
                win[ri][0] = win[ri][1];
                win[ri][1] = win[ri][2];
                if (rok[ri] && (w + 2 < W)) {
                    const u32 v = *(const u32*)(base + ((size_t)((h + ri - 1) * W + (w + 2))) * C);
                    float2 r;
                    r.x = fmaf(bf2f((u16)(v & 0xffff)), sc0, sh0);
                    r.y = fmaf(bf2f((u16)(v >> 16)),    sc1, sh1);
                    win[ri][2] = r;
                } else win[ri][2] = z;
            }
        }
    }
    const int idx = b * 32 + h;
    psum[c0 * 256 + idx] = s0;  psum[(c0 + 1) * 256 + idx] = s1;
    psq [c0 * 256 + idx] = q0;  psq [(c0 + 1) * 256 + idx] = q1;
    pmax[c0 * 256 + idx] = mx0; pmax[(c0 + 1) * 256 + idx] = mx1;
    pmin[c0 * 256 + idx] = mn0; pmin[(c0 + 1) * 256 + idx] = mn1;
}

// ---------------- K7: BN2 stats + per-(b,c) avg/max (one block per channel) ----------------
__global__ __launch_bounds__(256) void stats2_kernel(const float* __restrict__ psum,
                                                     const float* __restrict__ psq,
                                                     const float* __restrict__ pmax,
                                                     const float* __restrict__ pmin,
                                                     const float* __restrict__ g2,
                                                     const float* __restrict__ be2,
                                                     float* __restrict__ scale2,
                                                     float* __restrict__ shift2,
                                                     float* __restrict__ avgbn,
                                                     float* __restrict__ mxbn) {
    const int c = blockIdx.x;
    const int t = threadIdx.x;              // row index (b*32+h)
    const int base = c * 256 + t;
    float s  = psum[base];
    float q  = psq[base];
    float mx = pmax[base];
    float mn = pmin[base];
#pragma unroll
    for (int off = 1; off < 32; off <<= 1) {
        s += __shfl_xor(s, off);
        q += __shfl_xor(q, off);
        mx = fmaxf(mx, __shfl_xor(mx, off));
        mn = fminf(mn, __shfl_xor(mn, off));
    }
    __shared__ float bs[8], bq[8], bmx[8], bmn[8];
    __shared__ float sc_sh[2];
    if ((t & 31) == 0) {
        const int b = t >> 5;
        bs[b] = s; bq[b] = q; bmx[b] = mx; bmn[b] = mn;
    }
    __syncthreads();
    if (t == 0) {
        float S = 0.f, Q = 0.f;
#pragma unroll
        for (int b = 0; b < 8; ++b) { S += bs[b]; Q += bq[b]; }
        const float m = S * (1.0f / (float)M);
        const float var = Q * (1.0f / (float)M) - m * m;
        const float rstd = rsqrtf(var + EPS);
        const float sc = rstd * g2[c];
        const float sh = be2[c] - m * sc;
        scale2[c] = sc;
        shift2[c] = sh;
        sc_sh[0] = sc; sc_sh[1] = sh;
    }
    __syncthreads();
    if (t < 8) {
        const float sc = sc_sh[0], sh = sc_sh[1];
        avgbn[t * C + c] = bs[t] * (1.0f / (float)P) * sc + sh;
        mxbn[t * C + c] = (sc >= 0.f ? bmx[t] : bmn[t]) * sc + sh;
    }
}

// ---------------- K8: channel attention (wave-parallel dots) ----------------
__global__ __launch_bounds__(1024) void chatt_kernel(const float* __restrict__ avgbn,
                                                     const float* __restrict__ mxbn,
                                                     const float* __restrict__ caw1,
                                                     const float* __restrict__ caw2,
                                                     float* __restrict__ s_att) {
    const int b = blockIdx.x;
    const int t = threadIdx.x;
    const int wave = t >> 6, lane = t & 63;
    __shared__ float la[1024], lx[1024], ha[64], hm[64];
    la[t] = avgbn[b * C + t];
    lx[t] = mxbn[b * C + t];
    __syncthreads();
#pragma unroll
    for (int k = 0; k < 8; ++k) {
        const int u = wave * 8 + k;
        const int row = u & 63;
        const float* src = (u < 64) ? la : lx;
        const float4* wr = (const float4*)(caw1 + (size_t)row * C);
        float s = 0.f;
#pragma unroll
        for (int ch = 0; ch < 4; ++ch) {
            const float4 wv = wr[lane + 64 * ch];
            const float4 sv = *(const float4*)(src + 4 * lane + 256 * ch);
            s += wv.x * sv.x + wv.y * sv.y + wv.z * sv.z + wv.w * sv.w;
        }
#pragma unroll
        for (int off = 1; off < 64; off <<= 1) s += __shfl_xor(s, off);
        if (lane == 0) {
            s = fmaxf(s, 0.f);
            if (u < 64) ha[row] = s; else hm[row] = s;
        }
    }
    __syncthreads();
    {
        const float4* w2 = (const float4*)(caw2 + (size_t)t * 64);
        float s = 0.f;
#pragma unroll
        for (int j = 0; j < 16; ++j) {
            const float4 wv = w2[j];
            s += wv.x * (ha[j * 4 + 0] + hm[j * 4 + 0]);
            s += wv.y * (ha[j * 4 + 1] + hm[j * 4 + 1]);
            s += wv.z * (ha[j * 4 + 2] + hm[j * 4 + 2]);
            s += wv.w * (ha[j * 4 + 3] + hm[j * 4 + 3]);
        }
        s_att[b * C + t] = 1.0f / (1.0f + expf(-s));
    }
}

// ---------------- K9: y = s_att*bn2(t2) -> bf16 yb + per-row avg/max ----------------
__global__ __launch_bounds__(256) void yq_kernel(const u16* __restrict__ t2b,
                                                 const float* __restrict__ scale2,
                                                 const float* __restrict__ shift2,
                                                 const float* __restrict__ s_att,
                                                 u16* __restrict__ yb,
                                                 float* __restrict__ avg_o,
                                                 float* __restrict__ max_o) {
    const int row = blockIdx.x;       // b*P + p
    const int b = row >> 10;
    const int t = threadIdx.x;
    const int c0 = t * 4;
    const uint2 vv = *(const uint2*)(t2b + (size_t)row * C + c0);
    const float v0 = bf2f((u16)(vv.x & 0xffff));
    const float v1 = bf2f((u16)(vv.x >> 16));
    const float v2 = bf2f((u16)(vv.y & 0xffff));
    const float v3 = bf2f((u16)(vv.y >> 16));
    const float4 sc = *(const float4*)(scale2 + c0);
    const float4 sh = *(const float4*)(shift2 + c0);
    const float4 sa = *(const float4*)(s_att + (size_t)b * C + c0);
    const float y0 = fmaf(v0, sc.x, sh.x) * sa.x;
    const float y1 = fmaf(v1, sc.y, sh.y) * sa.y;
    const float y2 = fmaf(v2, sc.z, sh.z) * sa.z;
    const float y3 = fmaf(v3, sc.w, sh.w) * sa.w;
    uint2 o;
    o.x = ((u32)f2bf(y0)) | ((u32)f2bf(y1) << 16);
    o.y = ((u32)f2bf(y2)) | ((u32)f2bf(y3) << 16);
    *(uint2*)(yb + (size_t)row * C + c0) = o;
    float s = (y0 + y1) + (y2 + y3);
    float mx = fmaxf(fmaxf(y0, y1), fmaxf(y2, y3));
#pragma unroll
    for (int off = 32; off > 0; off >>= 1) {
        s += __shfl_down(s, off);
        mx = fmaxf(mx, __shfl_down(mx, off));
    }
    __shared__ float ss[4], sm[4];
    const int wave = t >> 6, lane = t & 63;
    if (lane == 0) { ss[wave] = s; sm[wave] = mx; }
    __syncthreads();
    if (t == 0) {
        const float S = ss[0] + ss[1] + ss[2] + ss[3];
        const float Mx = fmaxf(fmaxf(sm[0], sm[1]), fmaxf(sm[2], sm[3]));
        avg_o[row] = S * (1.0f / (float)C);
        max_o[row] = Mx;
    }
}

// ---------------- K10: 7x7 spatial conv + sigmoid (1 pixel/thread) ----------------
__global__ __launch_bounds__(1024) void spconv_kernel(const float* __restrict__ avg_o,
                                                      const float* __restrict__ max_o,
                                                      const float* __restrict__ sw,
                                                      const float* __restrict__ sb,
                                                      float* __restrict__ sp) {
    const int b = blockIdx.x;
    const int t = threadIdx.x;
    __shared__ float pa[P], pm[P], wsh[98];
    pa[t] = avg_o[b * P + t];
    pm[t] = max_o[b * P + t];
    if (t < 98) wsh[t] = sw[t];
    const float sbv = sb[0];
    __syncthreads();
    const int h = t >> 5, w = t & 31;
    float acc = sbv;
#pragma unroll
    for (int i = 0; i < 7; ++i) {
        const int hh = h + i - 3;
        if (hh < 0 || hh >= H) continue;
#pragma unroll
        for (int j = 0; j < 7; ++j) {
            const int ww = w + j - 3;
            if (ww < 0 || ww >= W) continue;
            const int pidx = hh * W + ww;
            acc = fmaf(wsh[i * 7 + j], pa[pidx], acc);
            acc = fmaf(wsh[49 + i * 7 + j], pm[pidx], acc);
        }
    }
    sp[b * P + t] = 1.0f / (1.0f + expf(-acc));
}

// ---------------- K15: final residual add + fused BN3 stats ----------------
__global__ __launch_bounds__(256) void final_kernel(const float* __restrict__ x,
                                                    const float* __restrict__ pre,
                                                    const float* __restrict__ chsum3,
                                                    const float* __restrict__ chsq3,
                                                    const float* __restrict__ g3,
                                                    const float* __restrict__ be3,
                                                    float* __restrict__ out) {
    __shared__ float lsc[256], lsh[256];
    const int t = threadIdx.x;
    {
        const float m = chsum3[t] * (1.0f / (float)M);
        const float var = chsq3[t] * (1.0f / (float)M) - m * m;
        const float rstd = rsqrtf(var + EPS);
        const float sc = rstd * g3[t];
        lsc[t] = sc;
        lsh[t] = be3[t] - m * sc;
    }
    __syncthreads();
    const int i = blockIdx.x * 256 + t;   // float4 index
    const int e = i * 4;
    const int d = e & 255;
    const float4 xv = *(const float4*)(x + e);
    const float4 pv = *(const float4*)(pre + e);
    const float4 sc = *(const float4*)(lsc + d);
    const float4 sh = *(const float4*)(lsh + d);
    float4 o;
    o.x = xv.x + fmaf(pv.x, sc.x, sh.x);
    o.y = xv.y + fmaf(pv.y, sc.y, sh.y);
    o.z = xv.z + fmaf(pv.z, sc.z, sh.z);
    o.w = xv.w + fmaf(pv.w, sc.w, sh.w);
    *(float4*)(out + e) = o;
}

extern "C" void kernel_launch(void* const* d_in, const int* in_sizes, int n_in,
                              void* d_out, int out_size, void* d_ws, size_t ws_size,
                              hipStream_t stream) {
    const float* x    = (const float*)d_in[0];
    const float* w1   = (const float*)d_in[1];
    const float* b1   = (const float*)d_in[2];
    const float* g1   = (const float*)d_in[3];
    const float* be1  = (const float*)d_in[4];
    const float* aw1  = (const float*)d_in[5];
    const float* ab1  = (const float*)d_in[6];
    const float* aw2  = (const float*)d_in[7];
    const float* ab2  = (const float*)d_in[8];
    const float* g2   = (const float*)d_in[9];
    const float* be2  = (const float*)d_in[10];
    const float* caw1 = (const float*)d_in[11];
    const float* caw2 = (const float*)d_in[12];
    const float* pw   = (const float*)d_in[13];
    const float* pb   = (const float*)d_in[14];
    const float* g3   = (const float*)d_in[15];
    const float* be3  = (const float*)d_in[16];
    const float* sw   = (const float*)d_in[17];
    const float* sb   = (const float*)d_in[18];
    float* out = (float*)d_out;
    float* ws = (float*)d_ws;

    // zero atomic accumulators
    hipMemsetAsync(ws, 0, WS_ACC_COUNT * sizeof(float), stream);

    float* chsum1  = ws + WS_CHSUM1;
    float* chsq1   = ws + WS_CHSQ1;
    float* gapsum  = ws + WS_GAPSUM;
    float* chsum3  = ws + WS_CHSUM3;
    float* chsq3   = ws + WS_CHSQ3;
    float* scale1  = ws + WS_SCALE1;
    float* shift1  = ws + WS_SHIFT1;
    float* kw      = ws + WS_KW;
    float* scale2  = ws + WS_SCALE2;
    float* shift2  = ws + WS_SHIFT2;
    float* avgbn   = ws + WS_AVGBN;
    float* mxbn    = ws + WS_MXBN;
    float* s_att   = ws + WS_SATT;
    float* avg_o   = ws + WS_AVGO;
    float* max_o   = ws + WS_MAXO;
    float* sp      = ws + WS_SP;
    float* psum2   = ws + WS_PSUM2;
    float* psq2    = ws + WS_PSQ2;
    float* pmax2   = ws + WS_PMAX2;
    float* pmin2   = ws + WS_PMIN2;
    float* pre     = ws + WS_PRE;
    u16* t1b = (u16*)(ws + WS_T1B);
    u16* t2b = (u16*)(ws + WS_T2B);
    u16* xb  = (u16*)(ws + WS_XB);
    u16* w1b = (u16*)(ws + WS_W1B);
    u16* pwb = (u16*)(ws + WS_PWB);
    u16* yb  = (u16*)(ws + WS_YB);

    // K0: all casts in one launch
    cvt_all_kernel<<<dim3(2560), 256, 0, stream>>>(x, w1, pw, xb, w1b, pwb);
    // K1: expand GEMM (bf16 MFMA, 128x64 tile, 1024 blocks) + bias + GELU -> bf16 t1 (LDS-staged
    //     coalesced stores), fused BN1 partial stats.  Dyn LDS = max(12288, 128*64*2) = 16384 B
    mfma_gemm_kernel<256, 0, C, 128, 64><<<dim3(C / 64, M / 128), 256, 16384, stream>>>(
        xb, w1b, b1, nullptr, t1b, chsum1, chsq1, gapsum);
    // K4: BN1 stats + gap + dynamic kernel weights (fused)
    dynmlp_kernel<<<dim3(B), 1024, 0, stream>>>(chsum1, chsq1, gapsum, g1, be1,
                                                aw1, ab1, aw2, ab2, scale1, shift1, kw);
    // K5: depthwise conv + GELU -> bf16 t2, fused BN2 partials (transposed layout)
    dwconv_kernel<<<dim3(C / 512, B * H), 256, 0, stream>>>(t1b, scale1, shift1, kw, t2b,
                                                            psum2, psq2, pmax2, pmin2);
    // K7: BN2 stats + per-(b,c) avg/max — one block per channel (1024 blocks)
    stats2_kernel<<<dim3(C), 256, 0, stream>>>(psum2, psq2, pmax2, pmin2, g2, be2,
                                               scale2, shift2, avgbn, mxbn);
    // K8: channel attention
    chatt_kernel<<<dim3(B), 1024, 0, stream>>>(avgbn, mxbn, caw1, caw2, s_att);
    // K9: y quantize + spatial stats
    yq_kernel<<<dim3(M), 256, 0, stream>>>(t2b, scale2, shift2, s_att, yb, avg_o, max_o);
    // K10: 7x7 conv + sigmoid
    spconv_kernel<<<dim3(B), 1024, 0, stream>>>(avg_o, max_o, sw, sb, sp);
    // K12: project GEMM (bf16 MFMA, 64x64 tile, 512 blocks) + sp/bias epilogue -> fp32 pre,
    //      fused BN3 stats.  Dyn LDS = 64*32*2 + 64*32*2 = 8192 B
    mfma_gemm_kernel<1024, 1, D, 64, 64><<<dim3(D / 64, M / 64), 256, 8192, stream>>>(
        yb, pwb, pb, sp, pre, chsum3, chsq3, nullptr);
    // K15: BN3 stats + final residual add (fused)
    final_kernel<<<dim3((M * D / 4) / 256), 256, 0, stream>>>(x, pre, chsum3, chsq3, g3, be3, out);
}